// Round 18
// baseline (43.648 us; speedup 1.0000x reference)
//
#include <hip/hip_runtime.h>
#include <cfloat>
#include <cmath>

#define NB     4
#define NPTS   4096
#define NLAT   512
#define RPTS   4                  // i-points per thread
#define CJ     128                // j-points per block
#define NJC    (NPTS / CJ)        // 32 j-chunks
#define NIH    4                  // i-quarters -> 1536 blocks, 6 waves/SIMD
#define NBLK   (3 * NB * NIH * NJC)   // 1536
#define NSUM   194                // 192 fold partials + KL + sizing

// ---------------------------------------------------------------------------
// Node 1: partial nearest-distance mins. (R16 config: CJ=128/RPTS=4/NIH=4,
// unroll 2, 6.3 MB partials. ONE change vs R16: mode-2 self-fix is a
// wave-uniform post-pass instead of inline per-pair selects, so the hot
// loop is identical for all modes.)
// Self mapping (verified absmax 0 in R16/R17): have iff jc>>3==iq;
// kself=(jc>>1)&3; aff iff tid>>7==jc&1; jself=tid&127.
// Single-writer partial stores -> no init/atomics, deterministic.
// ---------------------------------------------------------------------------
__global__ __launch_bounds__(256, 4) void k_min_dist(
    const float* __restrict__ pred_pos,
    const float* __restrict__ targ_pos,
    float* __restrict__ part_mins /* [3][NB][NJC][NPTS] */,
    unsigned int* __restrict__ counter)
{
    __shared__ float4 lds[CJ];    // 2 KiB

    const int tid  = threadIdx.x;
    const int blk  = blockIdx.x;
    const int jc   = blk & (NJC - 1);
    const int iq   = (blk >> 5) & 3;
    const int b    = (blk >> 7) & 3;
    const int mode = blk >> 9;

    if (blk == 0 && tid == 0) *counter = 0u;   // re-init every call

    const float* pts = (mode == 1) ? targ_pos : pred_pos;
    const float* oth = (mode == 0) ? targ_pos : pred_pos;

    // stage + transform j-chunk
    if (tid < CJ) {
        const float* ob = oth + ((size_t)b * NPTS + jc * CJ) * 3;
        const float x = ob[3 * tid], y = ob[3 * tid + 1], z = ob[3 * tid + 2];
        const float o2 = fmaf(z, z, fmaf(y, y, x * x));
        lds[tid] = make_float4(-2.f * x, -2.f * y, -2.f * z, o2);
    }

    const float* pb = pts + (size_t)b * NPTS * 3;
    float px[RPTS], py[RPTS], pz[RPTS], acc[RPTS];
    #pragma unroll
    for (int k = 0; k < RPTS; ++k) {
        const float* pp = pb + 3 * (iq * 1024 + (k << 8) + tid);
        px[k] = pp[0]; py[k] = pp[1]; pz[k] = pp[2];
        acc[k] = FLT_MAX;
    }
    __syncthreads();

    // ---- main loop: identical for all modes (R16's unroll 2) ----
    #pragma unroll 2
    for (int j = 0; j < CJ; j += 2) {
        const float4 o1 = lds[j];
        const float4 o2 = lds[j + 1];
        #pragma unroll
        for (int k = 0; k < RPTS; ++k) {
            float t1 = fmaf(o1.x, px[k], o1.w);
            t1 = fmaf(o1.y, py[k], t1);
            t1 = fmaf(o1.z, pz[k], t1);
            float t2 = fmaf(o2.x, px[k], o2.w);
            t2 = fmaf(o2.y, py[k], t2);
            t2 = fmaf(o2.z, pz[k], t2);
            acc[k] = fminf(acc[k], fminf(t1, t2));       // -> v_min3_f32
        }
    }

    // ---- mode-2 self-fix post-pass (wave-uniform, rare) ----
    if (mode == 2 && ((jc >> 3) == iq) && ((tid >> 7) == (jc & 1))) {
        const int kself = (jc >> 1) & 3;
        const int jself = tid & 127;
        float sx = px[0], sy = py[0], sz = pz[0];
        #pragma unroll
        for (int k = 1; k < RPTS; ++k) {
            sx = (k == kself) ? px[k] : sx;
            sy = (k == kself) ? py[k] : sy;
            sz = (k == kself) ? pz[k] : sz;
        }
        float accf = FLT_MAX;
        #pragma unroll 2
        for (int j = 0; j < CJ; j += 2) {
            const float4 o1 = lds[j];
            const float4 o2 = lds[j + 1];
            float f1 = fmaf(o1.x, sx, o1.w);
            f1 = fmaf(o1.y, sy, f1);
            f1 = fmaf(o1.z, sz, f1);
            f1 = (j == jself) ? FLT_MAX : f1;
            float f2 = fmaf(o2.x, sx, o2.w);
            f2 = fmaf(o2.y, sy, f2);
            f2 = fmaf(o2.z, sz, f2);
            f2 = ((j + 1) == jself) ? FLT_MAX : f2;
            accf = fminf(accf, fminf(f1, f2));
        }
        #pragma unroll
        for (int k = 0; k < RPTS; ++k)
            acc[k] = (k == kself) ? accf : acc[k];
    }

    float* mb = part_mins + (((size_t)mode * NB + b) * NJC + jc) * NPTS
                + iq * 1024;
    #pragma unroll
    for (int k = 0; k < RPTS; ++k) {
        const float p2 = fmaf(pz[k], pz[k], fmaf(py[k], py[k], px[k] * px[k]));
        mb[(k << 8) + tid] = acc[k] + p2;                // coalesced per k
    }
}

// ---------------------------------------------------------------------------
__device__ __forceinline__ float block_sum(float v, float* red)
{
    #pragma unroll
    for (int o = 32; o >= 1; o >>= 1) v += __shfl_xor(v, o);
    const int w = threadIdx.x >> 6;
    __syncthreads();
    if ((threadIdx.x & 63) == 0) red[w] = v;
    __syncthreads();
    return red[0] + red[1] + red[2] + red[3];
}

// ---------------------------------------------------------------------------
// Node 2 (R12/R14/R16-verified): fold + KL + sizing, election tail combines
// 194 scalars and writes the loss.
// ---------------------------------------------------------------------------
__global__ __launch_bounds__(256) void k_fold_final(
    const float* __restrict__ part_mins,
    const float* __restrict__ pred_sizing,
    const float* __restrict__ targ_sizing,
    const float* __restrict__ mu,
    const float* __restrict__ logvar,
    float* __restrict__ sums /* [194] */,
    float* __restrict__ sumsqs /* [194] */,
    unsigned int* __restrict__ counter,
    float* __restrict__ out)
{
    __shared__ float red[4];
    __shared__ float gs[12], gq[12];
    __shared__ unsigned int elect;
    const int blk = blockIdx.x, tid = threadIdx.x;

    if (blk < 192) {
        const int slice = blk & 15;
        const int b     = (blk >> 4) & 3;
        const int mode  = blk >> 6;
        const float* base = part_mins + ((size_t)mode * NB + b) * NJC * NPTS
                            + slice * 256 + tid;
        float m = FLT_MAX;
        #pragma unroll 8
        for (int jc = 0; jc < NJC; ++jc)
            m = fminf(m, base[(size_t)jc * NPTS]);
        const float s  = block_sum(m, red);
        const float s2 = block_sum(m * m, red);
        if (tid == 0) { sums[blk] = s; sumsqs[blk] = s2; }
    } else if (blk == 192) {
        float kls = 0.f;
        for (int i = tid; i < NB * NLAT; i += 256) {
            const float lv = logvar[i], m = mu[i];
            kls += 1.f + lv - m * m - expf(lv);
        }
        kls = block_sum(kls, red);
        if (tid == 0) { sums[192] = kls; sumsqs[192] = 0.f; }
    } else {
        const float4* ps = (const float4*)pred_sizing;
        const float4* ts = (const float4*)targ_sizing;
        float szs = 0.f;
        #pragma unroll 4
        for (int i = tid; i < NB * NPTS / 4; i += 256) {
            const float4 a = ps[i], c = ts[i];
            const float d0 = a.x - c.x, d1 = a.y - c.y;
            const float d2 = a.z - c.z, d3 = a.w - c.w;
            szs += fmaf(d0, d0, fmaf(d1, d1, fmaf(d2, d2, d3 * d3)));
        }
        szs = block_sum(szs, red);
        if (tid == 0) { sums[193] = szs; sumsqs[193] = 0.f; }
    }

    __syncthreads();
    if (tid == 0) {
        __threadfence();
        elect = (atomicAdd(counter, 1u) == (unsigned)(NSUM - 1));
    }
    __syncthreads();
    if (!elect) return;
    __threadfence();

    float v = 0.f, v2 = 0.f;
    if (tid < 192) { v = sums[tid]; v2 = sumsqs[tid]; }
    #pragma unroll
    for (int o = 1; o < 16; o <<= 1) {
        v  += __shfl_xor(v,  o);
        v2 += __shfl_xor(v2, o);
    }
    if (tid < 192 && (tid & 15) == 0) { gs[tid >> 4] = v; gq[tid >> 4] = v2; }
    __syncthreads();

    if (tid == 0) {
        float cd = 0.f, dens = 0.f;
        for (int b = 0; b < NB; ++b) {
            const float s01 = gs[b] + gs[4 + b];
            const float sS  = gs[8 + b];
            const float sS2 = gq[8 + b];
            cd += s01 / (float)NPTS;
            const float var = (sS2 - sS * sS / (float)NPTS) / (float)(NPTS - 1);
            dens += sqrtf(fmaxf(var, 0.f));
        }
        cd   /= (float)NB;
        dens /= (float)NB;
        const float kl     = -0.5f * sums[192] / (float)(NB * NLAT);
        const float sizing = sums[193] / (float)(NB * NPTS);
        out[0] = cd + 0.001f * kl + 0.1f * dens + 0.05f * sizing;
    }
}

// ---------------------------------------------------------------------------
extern "C" void kernel_launch(void* const* d_in, const int* in_sizes, int n_in,
                              void* d_out, int out_size, void* d_ws, size_t ws_size,
                              hipStream_t stream)
{
    const float* pred_pos    = (const float*)d_in[0];
    const float* pred_sizing = (const float*)d_in[1];
    const float* targ_pos    = (const float*)d_in[2];
    const float* targ_sizing = (const float*)d_in[3];
    const float* mu          = (const float*)d_in[4];
    const float* logvar      = (const float*)d_in[5];

    float* part_mins = (float*)d_ws;                             // 6.3 MiB
    float* sums      = part_mins + (size_t)3 * NB * NJC * NPTS;  // 194
    float* sumsqs    = sums + NSUM;                              // 194
    unsigned int* counter = (unsigned int*)(sumsqs + NSUM);      // 1

    k_min_dist<<<dim3(NBLK), dim3(256), 0, stream>>>(
        pred_pos, targ_pos, part_mins, counter);
    k_fold_final<<<dim3(NSUM), dim3(256), 0, stream>>>(
        part_mins, pred_sizing, targ_sizing, mu, logvar,
        sums, sumsqs, counter, (float*)d_out);
}

// Round 19
// 39.642 us; speedup vs baseline: 1.1011x; 1.1011x over previous
//
#include <hip/hip_runtime.h>
#include <cfloat>
#include <cmath>

#define NB     4
#define NPTS   4096
#define NLAT   512
#define RPTS   4                  // i-points per thread
#define CJ     128                // j-points per block
#define NJC    (NPTS / CJ)        // 32 j-chunks
#define NIH    4                  // i-quarters -> 1536 blocks, 6 waves/SIMD
#define NBLK   (3 * NB * NIH * NJC)   // 1536
#define NSUM   194                // 192 fold partials + KL + sizing

// ---------------------------------------------------------------------------
// Node 1: partial nearest-distance mins. (R16-verified best: 40.1 us.)
//   mode 0: pred -> target   mode 1: target -> pred   mode 2: pred self
// grid = 1536, block = 256. CJ=128/RPTS=4/NIH=4: partials 6.3 MB, ~28 VGPR
// live, 6 waves/SIMD. LDS stages 128 transformed j-points (o'=(-2o,|o|^2));
// per j-pair-chain 6 fma + 1 min3, inline self-fix chain for mode 2
// (uniform cost beats a post-pass straggler tail — R18 measured +3.5 us).
// Self mapping (verified absmax 0 in R16/R17/R18): have iff jc>>3==iq;
// kself=(jc>>1)&3; aff iff tid>>7==jc&1; jself=tid&127.
// Single-writer partial stores -> no init/atomics, deterministic.
// ---------------------------------------------------------------------------
__global__ __launch_bounds__(256, 4) void k_min_dist(
    const float* __restrict__ pred_pos,
    const float* __restrict__ targ_pos,
    float* __restrict__ part_mins /* [3][NB][NJC][NPTS] */,
    unsigned int* __restrict__ counter)
{
    __shared__ float4 lds[CJ];    // 2 KiB

    const int tid  = threadIdx.x;
    const int blk  = blockIdx.x;
    const int jc   = blk & (NJC - 1);
    const int iq   = (blk >> 5) & 3;
    const int b    = (blk >> 7) & 3;
    const int mode = blk >> 9;

    if (blk == 0 && tid == 0) *counter = 0u;   // re-init every call

    const float* pts = (mode == 1) ? targ_pos : pred_pos;
    const float* oth = (mode == 0) ? targ_pos : pred_pos;

    // stage + transform j-chunk
    if (tid < CJ) {
        const float* ob = oth + ((size_t)b * NPTS + jc * CJ) * 3;
        const float x = ob[3 * tid], y = ob[3 * tid + 1], z = ob[3 * tid + 2];
        const float o2 = fmaf(z, z, fmaf(y, y, x * x));
        lds[tid] = make_float4(-2.f * x, -2.f * y, -2.f * z, o2);
    }

    const float* pb = pts + (size_t)b * NPTS * 3;
    float px[RPTS], py[RPTS], pz[RPTS], acc[RPTS];
    #pragma unroll
    for (int k = 0; k < RPTS; ++k) {
        const float* pp = pb + 3 * (iq * 1024 + (k << 8) + tid);
        px[k] = pp[0]; py[k] = pp[1]; pz[k] = pp[2];
        acc[k] = FLT_MAX;
    }
    __syncthreads();

    if (mode != 2) {
        #pragma unroll 2
        for (int j = 0; j < CJ; j += 2) {
            const float4 o1 = lds[j];
            const float4 o2 = lds[j + 1];
            #pragma unroll
            for (int k = 0; k < RPTS; ++k) {
                float t1 = fmaf(o1.x, px[k], o1.w);
                t1 = fmaf(o1.y, py[k], t1);
                t1 = fmaf(o1.z, pz[k], t1);
                float t2 = fmaf(o2.x, px[k], o2.w);
                t2 = fmaf(o2.y, py[k], t2);
                t2 = fmaf(o2.z, pz[k], t2);
                acc[k] = fminf(acc[k], fminf(t1, t2));   // -> v_min3_f32
            }
        }
    } else {
        const bool have  = (jc >> 3) == iq;
        const int  kself = (jc >> 1) & 3;
        const bool aff   = have && ((tid >> 7) == (jc & 1));
        const int  jself = tid & 127;
        float sx = px[0], sy = py[0], sz = pz[0];
        #pragma unroll
        for (int k = 1; k < RPTS; ++k) {
            sx = (k == kself) ? px[k] : sx;
            sy = (k == kself) ? py[k] : sy;
            sz = (k == kself) ? pz[k] : sz;
        }
        float accf = FLT_MAX;
        #pragma unroll 2
        for (int j = 0; j < CJ; j += 2) {
            const float4 o1 = lds[j];
            const float4 o2 = lds[j + 1];
            #pragma unroll
            for (int k = 0; k < RPTS; ++k) {
                float t1 = fmaf(o1.x, px[k], o1.w);
                t1 = fmaf(o1.y, py[k], t1);
                t1 = fmaf(o1.z, pz[k], t1);
                float t2 = fmaf(o2.x, px[k], o2.w);
                t2 = fmaf(o2.y, py[k], t2);
                t2 = fmaf(o2.z, pz[k], t2);
                acc[k] = fminf(acc[k], fminf(t1, t2));
            }
            float f1 = fmaf(o1.x, sx, o1.w);
            f1 = fmaf(o1.y, sy, f1);
            f1 = fmaf(o1.z, sz, f1);
            f1 = (j == jself) ? FLT_MAX : f1;
            float f2 = fmaf(o2.x, sx, o2.w);
            f2 = fmaf(o2.y, sy, f2);
            f2 = fmaf(o2.z, sz, f2);
            f2 = ((j + 1) == jself) ? FLT_MAX : f2;
            accf = fminf(accf, fminf(f1, f2));
        }
        #pragma unroll
        for (int k = 0; k < RPTS; ++k)
            acc[k] = (aff && k == kself) ? accf : acc[k];
    }

    float* mb = part_mins + (((size_t)mode * NB + b) * NJC + jc) * NPTS
                + iq * 1024;
    #pragma unroll
    for (int k = 0; k < RPTS; ++k) {
        const float p2 = fmaf(pz[k], pz[k], fmaf(py[k], py[k], px[k] * px[k]));
        mb[(k << 8) + tid] = acc[k] + p2;                // coalesced per k
    }
}

// ---------------------------------------------------------------------------
__device__ __forceinline__ float block_sum(float v, float* red)
{
    #pragma unroll
    for (int o = 32; o >= 1; o >>= 1) v += __shfl_xor(v, o);
    const int w = threadIdx.x >> 6;
    __syncthreads();
    if ((threadIdx.x & 63) == 0) red[w] = v;
    __syncthreads();
    return red[0] + red[1] + red[2] + red[3];
}

// ---------------------------------------------------------------------------
// Node 2 (R12/R14/R16-verified): fold + KL + sizing, election tail combines
// 194 scalars and writes the loss.
// ---------------------------------------------------------------------------
__global__ __launch_bounds__(256) void k_fold_final(
    const float* __restrict__ part_mins,
    const float* __restrict__ pred_sizing,
    const float* __restrict__ targ_sizing,
    const float* __restrict__ mu,
    const float* __restrict__ logvar,
    float* __restrict__ sums /* [194] */,
    float* __restrict__ sumsqs /* [194] */,
    unsigned int* __restrict__ counter,
    float* __restrict__ out)
{
    __shared__ float red[4];
    __shared__ float gs[12], gq[12];
    __shared__ unsigned int elect;
    const int blk = blockIdx.x, tid = threadIdx.x;

    if (blk < 192) {
        const int slice = blk & 15;
        const int b     = (blk >> 4) & 3;
        const int mode  = blk >> 6;
        const float* base = part_mins + ((size_t)mode * NB + b) * NJC * NPTS
                            + slice * 256 + tid;
        float m = FLT_MAX;
        #pragma unroll 8
        for (int jc = 0; jc < NJC; ++jc)
            m = fminf(m, base[(size_t)jc * NPTS]);
        const float s  = block_sum(m, red);
        const float s2 = block_sum(m * m, red);
        if (tid == 0) { sums[blk] = s; sumsqs[blk] = s2; }
    } else if (blk == 192) {
        float kls = 0.f;
        for (int i = tid; i < NB * NLAT; i += 256) {
            const float lv = logvar[i], m = mu[i];
            kls += 1.f + lv - m * m - expf(lv);
        }
        kls = block_sum(kls, red);
        if (tid == 0) { sums[192] = kls; sumsqs[192] = 0.f; }
    } else {
        const float4* ps = (const float4*)pred_sizing;
        const float4* ts = (const float4*)targ_sizing;
        float szs = 0.f;
        #pragma unroll 4
        for (int i = tid; i < NB * NPTS / 4; i += 256) {
            const float4 a = ps[i], c = ts[i];
            const float d0 = a.x - c.x, d1 = a.y - c.y;
            const float d2 = a.z - c.z, d3 = a.w - c.w;
            szs += fmaf(d0, d0, fmaf(d1, d1, fmaf(d2, d2, d3 * d3)));
        }
        szs = block_sum(szs, red);
        if (tid == 0) { sums[193] = szs; sumsqs[193] = 0.f; }
    }

    __syncthreads();
    if (tid == 0) {
        __threadfence();
        elect = (atomicAdd(counter, 1u) == (unsigned)(NSUM - 1));
    }
    __syncthreads();
    if (!elect) return;
    __threadfence();

    float v = 0.f, v2 = 0.f;
    if (tid < 192) { v = sums[tid]; v2 = sumsqs[tid]; }
    #pragma unroll
    for (int o = 1; o < 16; o <<= 1) {
        v  += __shfl_xor(v,  o);
        v2 += __shfl_xor(v2, o);
    }
    if (tid < 192 && (tid & 15) == 0) { gs[tid >> 4] = v; gq[tid >> 4] = v2; }
    __syncthreads();

    if (tid == 0) {
        float cd = 0.f, dens = 0.f;
        for (int b = 0; b < NB; ++b) {
            const float s01 = gs[b] + gs[4 + b];
            const float sS  = gs[8 + b];
            const float sS2 = gq[8 + b];
            cd += s01 / (float)NPTS;
            const float var = (sS2 - sS * sS / (float)NPTS) / (float)(NPTS - 1);
            dens += sqrtf(fmaxf(var, 0.f));
        }
        cd   /= (float)NB;
        dens /= (float)NB;
        const float kl     = -0.5f * sums[192] / (float)(NB * NLAT);
        const float sizing = sums[193] / (float)(NB * NPTS);
        out[0] = cd + 0.001f * kl + 0.1f * dens + 0.05f * sizing;
    }
}

// ---------------------------------------------------------------------------
extern "C" void kernel_launch(void* const* d_in, const int* in_sizes, int n_in,
                              void* d_out, int out_size, void* d_ws, size_t ws_size,
                              hipStream_t stream)
{
    const float* pred_pos    = (const float*)d_in[0];
    const float* pred_sizing = (const float*)d_in[1];
    const float* targ_pos    = (const float*)d_in[2];
    const float* targ_sizing = (const float*)d_in[3];
    const float* mu          = (const float*)d_in[4];
    const float* logvar      = (const float*)d_in[5];

    float* part_mins = (float*)d_ws;                             // 6.3 MiB
    float* sums      = part_mins + (size_t)3 * NB * NJC * NPTS;  // 194
    float* sumsqs    = sums + NSUM;                              // 194
    unsigned int* counter = (unsigned int*)(sumsqs + NSUM);      // 1

    k_min_dist<<<dim3(NBLK), dim3(256), 0, stream>>>(
        pred_pos, targ_pos, part_mins, counter);
    k_fold_final<<<dim3(NSUM), dim3(256), 0, stream>>>(
        part_mins, pred_sizing, targ_sizing, mu, logvar,
        sums, sumsqs, counter, (float*)d_out);
}

// Round 20
// 39.036 us; speedup vs baseline: 1.1182x; 1.0155x over previous
//
#include <hip/hip_runtime.h>
#include <cfloat>
#include <cmath>

#define NB     4
#define NPTS   4096
#define NLAT   512
#define RPTS   8                  // i-points per thread (ds_read feeds 8 chains)
#define CJ     128                // j-points per block
#define NJC    (NPTS / CJ)        // 32 j-chunks -> partials stay 6.3 MB
#define NIH    2                  // i-halves -> 768 blocks, 12 waves/CU
#define NBLK   (3 * NB * NIH * NJC)   // 768
#define NSUM   194                // 192 fold partials + KL + sizing

// ---------------------------------------------------------------------------
// Node 1: partial nearest-distance mins.
//   mode 0: pred -> target   mode 1: target -> pred   mode 2: pred self
// grid = 768, block = 256. CJ=128/RPTS=8/NIH=2: same 6.3 MB partials as the
// verified R16 config, but each broadcast ds_read_b128 now feeds 8 fma
// chains -> LDS-pipe demand halves (model: 15.4 -> 7.7 us, VALU 9 us is
// the new limit). Live set ~60 VGPR under the launch_bounds cap.
// Self mapping (rederived for this tiling, hand-checked i=1500):
// have iff jc>>4==ihalf; kself=(jc&15)>>1; aff iff tid>>7==jc&1; jself=tid&127.
// Single-writer partial stores -> no init/atomics, deterministic.
// ---------------------------------------------------------------------------
__global__ __launch_bounds__(256, 4) void k_min_dist(
    const float* __restrict__ pred_pos,
    const float* __restrict__ targ_pos,
    float* __restrict__ part_mins /* [3][NB][NJC][NPTS] */,
    unsigned int* __restrict__ counter)
{
    __shared__ float4 lds[CJ];    // 2 KiB

    const int tid   = threadIdx.x;
    const int blk   = blockIdx.x;
    const int jc    = blk & (NJC - 1);
    const int ihalf = (blk >> 5) & 1;
    const int b     = (blk >> 6) & 3;
    const int mode  = blk >> 8;

    if (blk == 0 && tid == 0) *counter = 0u;   // re-init every call

    const float* pts = (mode == 1) ? targ_pos : pred_pos;
    const float* oth = (mode == 0) ? targ_pos : pred_pos;

    // stage + transform j-chunk
    if (tid < CJ) {
        const float* ob = oth + ((size_t)b * NPTS + jc * CJ) * 3;
        const float x = ob[3 * tid], y = ob[3 * tid + 1], z = ob[3 * tid + 2];
        const float o2 = fmaf(z, z, fmaf(y, y, x * x));
        lds[tid] = make_float4(-2.f * x, -2.f * y, -2.f * z, o2);
    }

    const float* pb = pts + (size_t)b * NPTS * 3;
    float px[RPTS], py[RPTS], pz[RPTS], acc[RPTS];
    #pragma unroll
    for (int k = 0; k < RPTS; ++k) {
        const float* pp = pb + 3 * (ihalf * 2048 + (k << 8) + tid);
        px[k] = pp[0]; py[k] = pp[1]; pz[k] = pp[2];
        acc[k] = FLT_MAX;
    }
    __syncthreads();

    if (mode != 2) {
        #pragma unroll 2
        for (int j = 0; j < CJ; j += 2) {
            const float4 o1 = lds[j];
            const float4 o2 = lds[j + 1];
            #pragma unroll
            for (int k = 0; k < RPTS; ++k) {
                float t1 = fmaf(o1.x, px[k], o1.w);
                t1 = fmaf(o1.y, py[k], t1);
                t1 = fmaf(o1.z, pz[k], t1);
                float t2 = fmaf(o2.x, px[k], o2.w);
                t2 = fmaf(o2.y, py[k], t2);
                t2 = fmaf(o2.z, pz[k], t2);
                acc[k] = fminf(acc[k], fminf(t1, t2));   // -> v_min3_f32
            }
        }
    } else {
        const bool have  = (jc >> 4) == ihalf;
        const int  kself = (jc & 15) >> 1;
        const bool aff   = have && ((tid >> 7) == (jc & 1));
        const int  jself = tid & 127;
        float sx = px[0], sy = py[0], sz = pz[0];
        #pragma unroll
        for (int k = 1; k < RPTS; ++k) {
            sx = (k == kself) ? px[k] : sx;
            sy = (k == kself) ? py[k] : sy;
            sz = (k == kself) ? pz[k] : sz;
        }
        float accf = FLT_MAX;
        #pragma unroll 2
        for (int j = 0; j < CJ; j += 2) {
            const float4 o1 = lds[j];
            const float4 o2 = lds[j + 1];
            #pragma unroll
            for (int k = 0; k < RPTS; ++k) {
                float t1 = fmaf(o1.x, px[k], o1.w);
                t1 = fmaf(o1.y, py[k], t1);
                t1 = fmaf(o1.z, pz[k], t1);
                float t2 = fmaf(o2.x, px[k], o2.w);
                t2 = fmaf(o2.y, py[k], t2);
                t2 = fmaf(o2.z, pz[k], t2);
                acc[k] = fminf(acc[k], fminf(t1, t2));
            }
            float f1 = fmaf(o1.x, sx, o1.w);
            f1 = fmaf(o1.y, sy, f1);
            f1 = fmaf(o1.z, sz, f1);
            f1 = (j == jself) ? FLT_MAX : f1;
            float f2 = fmaf(o2.x, sx, o2.w);
            f2 = fmaf(o2.y, sy, f2);
            f2 = fmaf(o2.z, sz, f2);
            f2 = ((j + 1) == jself) ? FLT_MAX : f2;
            accf = fminf(accf, fminf(f1, f2));
        }
        #pragma unroll
        for (int k = 0; k < RPTS; ++k)
            acc[k] = (aff && k == kself) ? accf : acc[k];
    }

    float* mb = part_mins + (((size_t)mode * NB + b) * NJC + jc) * NPTS
                + ihalf * 2048;
    #pragma unroll
    for (int k = 0; k < RPTS; ++k) {
        const float p2 = fmaf(pz[k], pz[k], fmaf(py[k], py[k], px[k] * px[k]));
        mb[(k << 8) + tid] = acc[k] + p2;                // coalesced per k
    }
}

// ---------------------------------------------------------------------------
__device__ __forceinline__ float block_sum(float v, float* red)
{
    #pragma unroll
    for (int o = 32; o >= 1; o >>= 1) v += __shfl_xor(v, o);
    const int w = threadIdx.x >> 6;
    __syncthreads();
    if ((threadIdx.x & 63) == 0) red[w] = v;
    __syncthreads();
    return red[0] + red[1] + red[2] + red[3];
}

// ---------------------------------------------------------------------------
// Node 2 (R12/R14/R16/R19-verified): fold + KL + sizing, election tail
// combines 194 scalars and writes the loss.
// ---------------------------------------------------------------------------
__global__ __launch_bounds__(256) void k_fold_final(
    const float* __restrict__ part_mins,
    const float* __restrict__ pred_sizing,
    const float* __restrict__ targ_sizing,
    const float* __restrict__ mu,
    const float* __restrict__ logvar,
    float* __restrict__ sums /* [194] */,
    float* __restrict__ sumsqs /* [194] */,
    unsigned int* __restrict__ counter,
    float* __restrict__ out)
{
    __shared__ float red[4];
    __shared__ float gs[12], gq[12];
    __shared__ unsigned int elect;
    const int blk = blockIdx.x, tid = threadIdx.x;

    if (blk < 192) {
        const int slice = blk & 15;
        const int b     = (blk >> 4) & 3;
        const int mode  = blk >> 6;
        const float* base = part_mins + ((size_t)mode * NB + b) * NJC * NPTS
                            + slice * 256 + tid;
        float m = FLT_MAX;
        #pragma unroll 8
        for (int jc = 0; jc < NJC; ++jc)
            m = fminf(m, base[(size_t)jc * NPTS]);
        const float s  = block_sum(m, red);
        const float s2 = block_sum(m * m, red);
        if (tid == 0) { sums[blk] = s; sumsqs[blk] = s2; }
    } else if (blk == 192) {
        float kls = 0.f;
        for (int i = tid; i < NB * NLAT; i += 256) {
            const float lv = logvar[i], m = mu[i];
            kls += 1.f + lv - m * m - expf(lv);
        }
        kls = block_sum(kls, red);
        if (tid == 0) { sums[192] = kls; sumsqs[192] = 0.f; }
    } else {
        const float4* ps = (const float4*)pred_sizing;
        const float4* ts = (const float4*)targ_sizing;
        float szs = 0.f;
        #pragma unroll 4
        for (int i = tid; i < NB * NPTS / 4; i += 256) {
            const float4 a = ps[i], c = ts[i];
            const float d0 = a.x - c.x, d1 = a.y - c.y;
            const float d2 = a.z - c.z, d3 = a.w - c.w;
            szs += fmaf(d0, d0, fmaf(d1, d1, fmaf(d2, d2, d3 * d3)));
        }
        szs = block_sum(szs, red);
        if (tid == 0) { sums[193] = szs; sumsqs[193] = 0.f; }
    }

    __syncthreads();
    if (tid == 0) {
        __threadfence();
        elect = (atomicAdd(counter, 1u) == (unsigned)(NSUM - 1));
    }
    __syncthreads();
    if (!elect) return;
    __threadfence();

    float v = 0.f, v2 = 0.f;
    if (tid < 192) { v = sums[tid]; v2 = sumsqs[tid]; }
    #pragma unroll
    for (int o = 1; o < 16; o <<= 1) {
        v  += __shfl_xor(v,  o);
        v2 += __shfl_xor(v2, o);
    }
    if (tid < 192 && (tid & 15) == 0) { gs[tid >> 4] = v; gq[tid >> 4] = v2; }
    __syncthreads();

    if (tid == 0) {
        float cd = 0.f, dens = 0.f;
        for (int b = 0; b < NB; ++b) {
            const float s01 = gs[b] + gs[4 + b];
            const float sS  = gs[8 + b];
            const float sS2 = gq[8 + b];
            cd += s01 / (float)NPTS;
            const float var = (sS2 - sS * sS / (float)NPTS) / (float)(NPTS - 1);
            dens += sqrtf(fmaxf(var, 0.f));
        }
        cd   /= (float)NB;
        dens /= (float)NB;
        const float kl     = -0.5f * sums[192] / (float)(NB * NLAT);
        const float sizing = sums[193] / (float)(NB * NPTS);
        out[0] = cd + 0.001f * kl + 0.1f * dens + 0.05f * sizing;
    }
}

// ---------------------------------------------------------------------------
extern "C" void kernel_launch(void* const* d_in, const int* in_sizes, int n_in,
                              void* d_out, int out_size, void* d_ws, size_t ws_size,
                              hipStream_t stream)
{
    const float* pred_pos    = (const float*)d_in[0];
    const float* pred_sizing = (const float*)d_in[1];
    const float* targ_pos    = (const float*)d_in[2];
    const float* targ_sizing = (const float*)d_in[3];
    const float* mu          = (const float*)d_in[4];
    const float* logvar      = (const float*)d_in[5];

    float* part_mins = (float*)d_ws;                             // 6.3 MiB
    float* sums      = part_mins + (size_t)3 * NB * NJC * NPTS;  // 194
    float* sumsqs    = sums + NSUM;                              // 194
    unsigned int* counter = (unsigned int*)(sumsqs + NSUM);      // 1

    k_min_dist<<<dim3(NBLK), dim3(256), 0, stream>>>(
        pred_pos, targ_pos, part_mins, counter);
    k_fold_final<<<dim3(NSUM), dim3(256), 0, stream>>>(
        part_mins, pred_sizing, targ_sizing, mu, logvar,
        sums, sumsqs, counter, (float*)d_out);
}